// Round 7
// baseline (169.473 us; speedup 1.0000x reference)
//
#include <hip/hip_runtime.h>

#define D 16
#define OUTD 153                 // 1 + 16 + 16 + 120
#define THREADS 256
#define GPW 2                    // 4-row groups per wave, fully unrolled

// Barrier-free + LDS-free + float4 stores:
//  - wave loads 4 rows as ONE coalesced 256B dword load (lane L -> x_flat[g*64+L])
//  - per 4-row group the output is 612 dwords = 153 float4; lane L of round k owns
//    float4 f = k*64+L (k=0,1 full; k=2 masked to 25 lanes)
//  - each element: val = ones ? 1 : x_i * (quad ? x_j : 1) * scale, x gathered by
//    __shfl; descriptors depend only on lane -> computed once, compile-time indexed
//  - stores: global_store_dwordx4, 1024B fully coalesced (R1/R5 vs R2/R4 evidence:
//    16B/lane store width is worth ~20 us over dword stores)
//  - R6 bug fixed: ones column occurs at dw = {0,153,306,459} per group (one per row),
//    not just (k=0,lane=0) -> now a per-element descriptor flag on[kk]

__global__ __launch_bounds__(THREADS) void taylor_fm_kernel(const float* __restrict__ x,
                                                            float* __restrict__ out,
                                                            int nrows) {
    const int tid  = threadIdx.x;
    const int lane = tid & 63;
    const int wid  = tid >> 6;
    const int ngroups = nrows >> 2;                        // 4 rows per group
    const long long g0 = ((long long)blockIdx.x * 4 + wid) * GPW;

    // ---- per-lane descriptors for 12 elements (3 rounds x 4 dwords) ----
    int   sa[12], sb[12];      // source lanes for x_i, x_j
    float sc[12];              // scale
    bool  qd[12];              // true: val = a*b*sc ; false: val = a*sc
    bool  on[12];              // true: val = 1.0 (ones column)
#pragma unroll
    for (int kk = 0; kk < 12; ++kk) {
        const int k  = kk >> 2;                            // round
        const int e  = kk & 3;                             // element within float4
        const int f  = k * 64 + lane;                      // float4 index in group
        const int dw = 4 * f + e;                          // dword index in group [0,612)
        const int row = dw / OUTD;                         // runtime div-by-const, once
        const int col = dw - row * OUTD;
        int i = 0, j = 0; float s = 0.0f; bool q = true; bool one = false;
        if (col == 0)      { one = true; }
        else if (col < 17) { i = col - 1;  s = 0.5f; q = false; }
        else if (col < 33) { i = col - 17; j = i; s = 0.17677669529663687f; }
        else               { int t = col - 33; i = 0;
                             while (t >= 15 - i) { t -= 15 - i; ++i; }
                             j = i + 1 + t; s = 0.25f; }
        sa[kk] = (row & 3) * 16 + i;                       // row&3: garbage rows masked at store
        sb[kk] = (row & 3) * 16 + j;
        sc[kk] = s; qd[kk] = q; on[kk] = one;
    }

    // ---- issue all group loads upfront (1 coalesced dword/lane per group) ----
    float xv[GPW];
#pragma unroll
    for (int g = 0; g < GPW; ++g) {
        const long long grp = g0 + g;
        xv[g] = (grp < ngroups) ? x[grp * 64 + lane] : 0.f;
    }

#pragma unroll
    for (int g = 0; g < GPW; ++g) {
        const long long grp = g0 + g;
        if (grp >= ngroups) break;
        const float v = xv[g];
        float4* gbase = reinterpret_cast<float4*>(out + grp * (4 * OUTD));  // 2448B, 16B-aligned
#pragma unroll
        for (int k = 0; k < 3; ++k) {
            float o[4];
#pragma unroll
            for (int e = 0; e < 4; ++e) {
                const int kk = k * 4 + e;
                const float a  = __shfl(v, sa[kk], 64);
                const float b  = __shfl(v, sb[kk], 64);
                const float be = qd[kk] ? b : 1.0f;
                o[e] = on[kk] ? 1.0f : a * be * sc[kk];
            }
            const int f = k * 64 + lane;
            if (f < OUTD) gbase[f] = make_float4(o[0], o[1], o[2], o[3]);
        }
    }
}

extern "C" void kernel_launch(void* const* d_in, const int* in_sizes, int n_in,
                              void* d_out, int out_size, void* d_ws, size_t ws_size,
                              hipStream_t stream) {
    const float* x = (const float*)d_in[0];
    float* out = (float*)d_out;
    const int nrows = in_sizes[0] / D;                     // 4*16*8192 = 524288
    const int ngroups = nrows >> 2;                        // 131072
    const int waves_needed = (ngroups + GPW - 1) / GPW;    // 65536
    const int blocks = (waves_needed + 3) / 4;             // 16384
    taylor_fm_kernel<<<blocks, THREADS, 0, stream>>>(x, out, nrows);
}

// Round 8
// 80.197 us; speedup vs baseline: 2.1132x; 2.1132x over previous
//
#include <hip/hip_runtime.h>

#define D 16
#define OUTD 153                 // 1 + 16 + 16 + 120
#define THREADS 256
#define GPW 8                    // 4-row groups per wave (131072 / 8 = 16384 waves exactly)

// Barrier-free + LDS-free + float4 stores (R7 structure), with ALL descriptor
// computation straight-line so every array is compile-time-indexed -> registers
// (R7's 169us: `while` inside the unrolled descriptor loop + `break` in the group
//  loop blocked unrolling -> dynamic indexing -> scratch on the hot path).
//  - triangle inverse in closed form: i = floor((31 - sqrt(961 - 8t))/2); the
//    sqrt argument is (31-2i)^2 exactly at row starts -> boundary-exact.
//  - wave loads 4 rows as ONE coalesced 256B dword load; per group, lane L of
//    round k owns float4 f = k*64+L (k=0,1 full; k=2 lanes 0..24).
//  - stores: global_store_dwordx4, 1024B fully coalesced, no barriers anywhere.

__global__ __launch_bounds__(THREADS) void taylor_fm_kernel(const float* __restrict__ x,
                                                            float* __restrict__ out,
                                                            int nrows) {
    const int tid  = threadIdx.x;
    const int lane = tid & 63;
    const int wid  = tid >> 6;
    const int ngroups = nrows >> 2;                        // 4 rows per group
    const long long g0 = ((long long)blockIdx.x * 4 + wid) * GPW;

    // ---- per-lane descriptors, 12 elements (3 rounds x 4 dwords), straight-line ----
    int   sa[12], sb[12];      // source lanes for x_i, x_j
    float sc[12];              // scale
    bool  qd[12];              // true: val = a*b*sc ; false: val = a*sc
    bool  on[12];              // true: val = 1.0 (ones column)
#pragma unroll
    for (int kk = 0; kk < 12; ++kk) {
        const int k  = kk >> 2;                            // round
        const int e  = kk & 3;                             // element within float4
        const int f  = k * 64 + lane;                      // float4 index in group
        const int dw = 4 * f + e;                          // dword index in group [0,612)
        const int row = dw / OUTD;                         // const-div -> magic mul
        const int col = dw - row * OUTD;
        int i = 0, j = 0; float s = 0.0f; bool q = true, one = false;
        if (col == 0)      { one = true; }
        else if (col < 17) { i = col - 1;  s = 0.5f; q = false; }
        else if (col < 33) { i = col - 17; j = i; s = 0.17677669529663687f; }
        else {                                             // upper triangle, closed form
            const int t = col - 33;                        // 0..119
            i = (int)((31.0 - sqrt(961.0 - 8.0 * (double)t)) * 0.5);
            const int base = i * (31 - i) / 2;             // first t of row i
            j = i + 1 + (t - base);
            s = 0.25f;
        }
        sa[kk] = (row & 3) * 16 + i;                       // row&3 harmless for masked lanes
        sb[kk] = (row & 3) * 16 + j;
        sc[kk] = s; qd[kk] = q; on[kk] = one;
    }

    // ---- issue all group loads upfront (1 coalesced 256B dword load per group) ----
    float xv[GPW];
#pragma unroll
    for (int g = 0; g < GPW; ++g) {
        const long long grp = g0 + g;
        xv[g] = (grp < ngroups) ? x[grp * 64 + lane] : 0.f;
    }

#pragma unroll
    for (int g = 0; g < GPW; ++g) {
        const long long grp = g0 + g;
        if (grp < ngroups) {                               // no break: keep loop unrolled
            const float v = xv[g];
            float4* gbase = reinterpret_cast<float4*>(out + grp * (4 * OUTD));  // 2448B
#pragma unroll
            for (int k = 0; k < 3; ++k) {
                float o[4];
#pragma unroll
                for (int e = 0; e < 4; ++e) {
                    const int kk = k * 4 + e;
                    const float a  = __shfl(v, sa[kk], 64);
                    const float b  = __shfl(v, sb[kk], 64);
                    const float be = qd[kk] ? b : 1.0f;
                    o[e] = on[kk] ? 1.0f : a * be * sc[kk];
                }
                const int f = k * 64 + lane;
                if (f < OUTD) gbase[f] = make_float4(o[0], o[1], o[2], o[3]);
            }
        }
    }
}

extern "C" void kernel_launch(void* const* d_in, const int* in_sizes, int n_in,
                              void* d_out, int out_size, void* d_ws, size_t ws_size,
                              hipStream_t stream) {
    const float* x = (const float*)d_in[0];
    float* out = (float*)d_out;
    const int nrows = in_sizes[0] / D;                     // 4*16*8192 = 524288
    const int ngroups = nrows >> 2;                        // 131072
    const int waves_needed = (ngroups + GPW - 1) / GPW;    // 16384
    const int blocks = (waves_needed + 3) / 4;             // 4096
    taylor_fm_kernel<<<blocks, THREADS, 0, stream>>>(x, out, nrows);
}

// Round 9
// 77.796 us; speedup vs baseline: 2.1784x; 1.0309x over previous
//
#include <hip/hip_runtime.h>

#define D 16
#define OUTD 153                      // 1 + 16 + 16 + 120
#define THREADS 256
#define WROWS 8                       // rows per wave-tile
#define WTILE_FLOATS (WROWS * OUTD)   // 1224 floats = 4896 B per wave slab

// Wave-private tiles: each wave owns 8 rows end-to-end in its own LDS slab.
//  - NO __syncthreads anywhere (cross-lane LDS RAW is same-wave -> one lgkmcnt(0))
//  - emit with x in registers (R4's proven fast path), 8-way divergent but cheap
//  - readback + store: flat float4, 4896B contiguous per wave, fully coalesced
//  - 8 blocks/CU x 4 independent waves = 32 independent store streams per CU
//    (R4 had 8 barrier-locked groups; R8 showed barrier-free alone isn't enough --
//     the shuffle crossbar was the cost; this keeps the LDS-staged pipeline)

template<int LO, int HI>
__device__ __forceinline__ void emit_cols(const float xv[D], float* dst) {
    if (LO <= 0 && 0 < HI) dst[0] = 1.0f;
#pragma unroll
    for (int k = 0; k < D; ++k) {
        const int c1 = 1 + k;                    // x / 16^0.25
        if (c1 >= LO && c1 < HI) dst[c1] = xv[k] * 0.5f;
        const int c2 = 17 + k;                   // x^2 / (4*sqrt(2))
        if (c2 >= LO && c2 < HI) dst[c2] = xv[k] * xv[k] * 0.17677669529663687f;
    }
#pragma unroll
    for (int i = 0; i < D; ++i) {
#pragma unroll
        for (int j = i + 1; j < D; ++j) {        // x_i*x_j / 4
            const int c = 33 + (15 * i - (i * (i - 1)) / 2) + (j - i - 1);
            if (c >= LO && c < HI) dst[c] = xv[i] * xv[j] * 0.25f;
        }
    }
}

__global__ __launch_bounds__(THREADS) void taylor_fm_kernel(const float* __restrict__ x,
                                                            float* __restrict__ out,
                                                            int nrows) {
    __shared__ float olds[4 * WTILE_FLOATS];     // 19584 B -> 8 blocks/CU (32 waves)
    const int lane = threadIdx.x & 63;
    const int wid  = threadIdx.x >> 6;
    const long long wt = (long long)blockIdx.x * 4 + wid;   // wave-tile id
    const long long r0 = wt * WROWS;
    if (r0 >= nrows) return;

    float* wlds = olds + wid * WTILE_FLOATS;     // this wave's private slab

    // ---- load this lane's row (8 lanes share a row -> L1 absorbs redundancy) ----
    const int r = lane & 7;                      // row within tile
    const float4* xrow = reinterpret_cast<const float4*>(x + (size_t)(r0 + r) * D);
    float xv[D];
#pragma unroll
    for (int m = 0; m < 4; ++m) {
        float4 v = xrow[m];
        xv[4 * m + 0] = v.x; xv[4 * m + 1] = v.y;
        xv[4 * m + 2] = v.z; xv[4 * m + 3] = v.w;
    }

    // ---- emit into wave-private LDS; banks (25r+c)%32 distinct per branch ----
    {
        float* dst = wlds + r * OUTD;
        switch (lane >> 3) {                     // 8-way divergent, ~55 slots each
            case 0: emit_cols<0,   20 >(xv, dst); break;
            case 1: emit_cols<20,  39 >(xv, dst); break;
            case 2: emit_cols<39,  58 >(xv, dst); break;
            case 3: emit_cols<58,  77 >(xv, dst); break;
            case 4: emit_cols<77,  96 >(xv, dst); break;
            case 5: emit_cols<96,  115>(xv, dst); break;
            case 6: emit_cols<115, 134>(xv, dst); break;
            case 7: emit_cols<134, 153>(xv, dst); break;
        }
    }

    // Same-wave DS drain: all 64 lanes' ds_writes retire before any ds_read below.
    asm volatile("s_waitcnt lgkmcnt(0)" ::: "memory");

    // ---- flat float4 readback + coalesced store (4896 B contiguous, 16B-aligned) ----
    const float4* lsrc = reinterpret_cast<const float4*>(wlds);
    float4* gdst = reinterpret_cast<float4*>(out + r0 * OUTD);
#pragma unroll
    for (int k = 0; k < 5; ++k) {                // 306 = 4*64 + 50
        const int g = k * 64 + lane;
        if (g < WTILE_FLOATS / 4) gdst[g] = lsrc[g];
    }
}

extern "C" void kernel_launch(void* const* d_in, const int* in_sizes, int n_in,
                              void* d_out, int out_size, void* d_ws, size_t ws_size,
                              hipStream_t stream) {
    const float* x = (const float*)d_in[0];
    float* out = (float*)d_out;
    const int nrows = in_sizes[0] / D;           // 4*16*8192 = 524288
    const int wtiles = (nrows + WROWS - 1) / WROWS;          // 65536
    const int blocks = (wtiles + 3) / 4;                     // 16384
    taylor_fm_kernel<<<blocks, THREADS, 0, stream>>>(x, out, nrows);
}

// Round 11
// 63.414 us; speedup vs baseline: 2.6725x; 1.2268x over previous
//
#include <hip/hip_runtime.h>

#define D 16
#define OUTD 153                 // 1 + 16 + 16 + 120
#define TILE_ROWS 32
#define THREADS 256

typedef float f32x4 __attribute__((ext_vector_type(4)));   // native vector: OK for nontemporal builtin

// R4 structure (best so far: 67.8us) + ONE change: nontemporal output stores.
// Output (306MB) is write-once/never-read and larger than LLC (256MB); normal
// stores write-allocate and evict the 32MB input x, forcing HBM re-misses at
// every block head. `nt` stores (evict-first) keep x resident in LLC.

template<int LO, int HI>
__device__ __forceinline__ void emit_cols(const float xv[D], float* dst) {
    if (LO <= 0 && 0 < HI) dst[0] = 1.0f;
#pragma unroll
    for (int k = 0; k < D; ++k) {
        const int c1 = 1 + k;                    // x / 16^0.25
        if (c1 >= LO && c1 < HI) dst[c1] = xv[k] * 0.5f;
        const int c2 = 17 + k;                   // x^2 / (4*sqrt(2))
        if (c2 >= LO && c2 < HI) dst[c2] = xv[k] * xv[k] * 0.17677669529663687f;
    }
#pragma unroll
    for (int i = 0; i < D; ++i) {
#pragma unroll
        for (int j = i + 1; j < D; ++j) {        // x_i*x_j / 4
            const int c = 33 + (15 * i - (i * (i - 1)) / 2) + (j - i - 1);
            if (c >= LO && c < HI) dst[c] = xv[i] * xv[j] * 0.25f;
        }
    }
}

__global__ __launch_bounds__(THREADS) void taylor_fm_kernel(const float* __restrict__ x,
                                                            float* __restrict__ out,
                                                            int nrows) {
    __shared__ float olds[TILE_ROWS * OUTD];     // 19.125 KiB -> 8 blocks/CU, 32 waves/CU
    const int tid = threadIdx.x;
    const int r   = tid & 31;                    // row within tile (8 threads per row)
    const int r8  = tid >> 5;                    // col-range id
    const int r0  = blockIdx.x * TILE_ROWS;
    const int row = r0 + r;

    if (row < nrows) {
        const float4* xrow = reinterpret_cast<const float4*>(x + (size_t)row * D);
        float xv[D];
#pragma unroll
        for (int m = 0; m < 4; ++m) {
            float4 v = xrow[m];
            xv[4 * m + 0] = v.x; xv[4 * m + 1] = v.y;
            xv[4 * m + 2] = v.z; xv[4 * m + 3] = v.w;
        }
        // banks (25r+c)%32 bijective over r -> conflict-free
        float* dst = olds + r * OUTD;
        switch (r8) {
            case 0: emit_cols<0,   20 >(xv, dst); break;
            case 1: emit_cols<20,  39 >(xv, dst); break;
            case 2: emit_cols<39,  58 >(xv, dst); break;
            case 3: emit_cols<58,  77 >(xv, dst); break;
            case 4: emit_cols<77,  96 >(xv, dst); break;
            case 5: emit_cols<96,  115>(xv, dst); break;
            case 6: emit_cols<115, 134>(xv, dst); break;
            case 7: emit_cols<134, 153>(xv, dst); break;
        }
    }
    __syncthreads();

    // Flat, fully coalesced float4 NONTEMPORAL stores (evict-first: stream bypasses
    // LLC retention, keeping x cached). Chunk = 19584B, 16B-aligned, nelem mult of 4.
    const int nrow_blk = min(TILE_ROWS, nrows - r0);
    const int nelem = nrow_blk * OUTD;
    const int nf4 = nelem >> 2;
    f32x4* gout = reinterpret_cast<f32x4*>(out + (size_t)r0 * OUTD);
    const f32x4* lsrc = reinterpret_cast<const f32x4*>(olds);
    for (int g = tid; g < nf4; g += THREADS)
        __builtin_nontemporal_store(lsrc[g], gout + g);
    if (tid < (nelem & 3))
        __builtin_nontemporal_store(olds[nf4 * 4 + tid], out + (size_t)r0 * OUTD + nf4 * 4 + tid);
}

extern "C" void kernel_launch(void* const* d_in, const int* in_sizes, int n_in,
                              void* d_out, int out_size, void* d_ws, size_t ws_size,
                              hipStream_t stream) {
    const float* x = (const float*)d_in[0];
    float* out = (float*)d_out;
    const int nrows = in_sizes[0] / D;           // 4*16*8192 = 524288
    const int blocks = (nrows + TILE_ROWS - 1) / TILE_ROWS;   // 16384
    taylor_fm_kernel<<<blocks, THREADS, 0, stream>>>(x, out, nrows);
}